// Round 3
// baseline (2045.632 us; speedup 1.0000x reference)
//
#include <hip/hip_runtime.h>
#include <hip/hip_bf16.h>
#include <math.h>

#define TAU 0.5f

// ---------------------------------------------------------------------------
// CSR build: histogram -> single-block exclusive scan -> scatter.
// ---------------------------------------------------------------------------
__global__ void hist_kernel(const int* __restrict__ row, int* __restrict__ deg, int E) {
    int e = blockIdx.x * 256 + threadIdx.x;
    if (e < E) atomicAdd(&deg[row[e]], 1);
}

__global__ void scan_kernel(const int* __restrict__ deg, int* __restrict__ row_ptr,
                            int* __restrict__ next, int n) {
    __shared__ int sums[1024];
    int t = threadIdx.x;
    int C = (n + 1023) >> 10;
    int s0 = t * C;
    int s1 = min(s0 + C, n);
    int local = 0;
    for (int i = s0; i < s1; ++i) local += deg[i];
    sums[t] = local;
    __syncthreads();
    for (int off = 1; off < 1024; off <<= 1) {
        int v = (t >= off) ? sums[t - off] : 0;
        __syncthreads();
        sums[t] += v;
        __syncthreads();
    }
    int run = (t == 0) ? 0 : sums[t - 1];
    for (int i = s0; i < s1; ++i) {
        int d = deg[i];
        row_ptr[i] = run;
        next[i] = run;
        run += d;
    }
    if (t == 0) row_ptr[n] = sums[1023];
}

__global__ void scatter_kernel(const int* __restrict__ row, const int* __restrict__ col,
                               const float* __restrict__ val, int* __restrict__ next,
                               int* __restrict__ col_s, float* __restrict__ val_s, int E) {
    int e = blockIdx.x * 256 + threadIdx.x;
    if (e >= E) return;
    int p = atomicAdd(&next[row[e]], 1);
    col_s[p] = col[e];
    val_s[p] = val[e];
}

// ---------------------------------------------------------------------------
// Fused GNN layer: one wave per row (grid-stride).
//   acc[lane] = sum_e val[e] * X[col[e], lane]        (CSR gather, unroll 4)
//   h[lane]   = sum_k acc[k] * W[lane, k]             (shfl matvec vs LDS W^T)
//   Xn[row]   = X[row] + relu(h)                      (residual, double-buffer)
//   if s: s[row] = dot(Xn[row], Ws)                   (folded score, layer 2)
// ---------------------------------------------------------------------------
__global__ void fused_layer_kernel(const int* __restrict__ row_ptr,
                                   const int* __restrict__ col_s,
                                   const float* __restrict__ val_s,
                                   const float* __restrict__ X,
                                   const float* __restrict__ W,
                                   float* __restrict__ Xn,
                                   float* __restrict__ s,
                                   const float* __restrict__ Wsv, int n) {
    __shared__ float Wt[64 * 65];
    int tid = threadIdx.x;
    for (int i = tid; i < 4096; i += 256) {
        int j = i >> 6, k = i & 63;     // W[j,k] row-major
        Wt[k * 65 + j] = W[i];          // transpose into LDS, stride 65
    }
    __syncthreads();
    int lane = tid & 63;
    int wv = tid >> 6;
    float wsl = (s != nullptr) ? Wsv[lane] : 0.f;
    int nwaves = gridDim.x * 4;
    for (int row = blockIdx.x * 4 + wv; row < n; row += nwaves) {
        int p = row_ptr[row];
        int end = row_ptr[row + 1];
        float a0 = 0.f, a1 = 0.f, a2 = 0.f, a3 = 0.f;
        for (; p + 4 <= end; p += 4) {
            int c0 = col_s[p], c1 = col_s[p + 1], c2 = col_s[p + 2], c3 = col_s[p + 3];
            float v0 = val_s[p], v1 = val_s[p + 1], v2 = val_s[p + 2], v3 = val_s[p + 3];
            a0 += v0 * X[(size_t)c0 * 64 + lane];
            a1 += v1 * X[(size_t)c1 * 64 + lane];
            a2 += v2 * X[(size_t)c2 * 64 + lane];
            a3 += v3 * X[(size_t)c3 * 64 + lane];
        }
        for (; p < end; ++p) a0 += val_s[p] * X[(size_t)col_s[p] * 64 + lane];
        float acc = (a0 + a1) + (a2 + a3);
        float h = 0.f;
#pragma unroll
        for (int k = 0; k < 64; ++k)
            h += __shfl(acc, k, 64) * Wt[k * 65 + lane];
        float xv = X[(size_t)row * 64 + lane] + fmaxf(h, 0.f);
        Xn[(size_t)row * 64 + lane] = xv;
        if (s != nullptr) {
            float d = xv * wsl;
            for (int off = 32; off; off >>= 1) d += __shfl_down(d, off, 64);
            if (lane == 0) s[row] = d;
        }
    }
}

// ---------------------------------------------------------------------------
// Fused power iteration: 16 lanes per row.
//   s0    = (L v_in)[row]        (coalesced 16-wide CSR segment reads)
//   scale = prev inv-norm (folded normalize; sign(s*scale)==sign(s0))
//   w     = s0*scale - TAU*sign(s0) ; v_out[row] = w ; norm_out += w^2
// ---------------------------------------------------------------------------
__global__ void power_iter_kernel(const int* __restrict__ row_ptr,
                                  const int* __restrict__ col_s,
                                  const float* __restrict__ val_s,
                                  const float* __restrict__ v_in,
                                  float* __restrict__ v_out,
                                  const float* __restrict__ norm_prev,
                                  float* __restrict__ norm_out, int n) {
    int g = blockIdx.x * 256 + threadIdx.x;
    int row = g >> 4;
    int t = g & 15;
    float sq = 0.f;
    if (row < n) {
        int p = row_ptr[row] + t;
        int end = row_ptr[row + 1];
        float s0 = 0.f;
        for (; p < end; p += 16) s0 += val_s[p] * v_in[col_s[p]];
        s0 += __shfl_xor(s0, 8, 16);
        s0 += __shfl_xor(s0, 4, 16);
        s0 += __shfl_xor(s0, 2, 16);
        s0 += __shfl_xor(s0, 1, 16);
        if (t == 0) {
            float scale = 1.f;
            if (norm_prev) scale = 1.f / fmaxf(sqrtf(*norm_prev), 1e-12f);
            float sg = (s0 > 0.f) ? 1.f : ((s0 < 0.f) ? -1.f : 0.f);
            float w = s0 * scale - TAU * sg;
            v_out[row] = w;
            sq = w * w;
        }
    }
    for (int off = 32; off; off >>= 1) sq += __shfl_down(sq, off, 64);
    __shared__ float sh[4];
    int lane = threadIdx.x & 63, wv = threadIdx.x >> 6;
    if (lane == 0) sh[wv] = sq;
    __syncthreads();
    if (threadIdx.x == 0) atomicAdd(norm_out, sh[0] + sh[1] + sh[2] + sh[3]);
}

// ---------------------------------------------------------------------------
// out[i] = v[i] / max(sqrt(ss), 1e-12)
// ---------------------------------------------------------------------------
__global__ void finalize_kernel(const float* __restrict__ v,
                                const float* __restrict__ norm_ptr,
                                float* __restrict__ out, int n) {
    int i = blockIdx.x * 256 + threadIdx.x;
    if (i >= n) return;
    float inv = 1.f / fmaxf(sqrtf(*norm_ptr), 1e-12f);
    out[i] = v[i] * inv;
}

extern "C" void kernel_launch(void* const* d_in, const int* in_sizes, int n_in,
                              void* d_out, int out_size, void* d_ws, size_t ws_size,
                              hipStream_t stream) {
    const int* A_row = (const int*)d_in[0];
    const int* A_col = (const int*)d_in[1];
    const float* A_val = (const float*)d_in[2];
    const int* L_row = (const int*)d_in[3];
    const int* L_col = (const int*)d_in[4];
    const float* L_val = (const float*)d_in[5];
    const float* embed = (const float*)d_in[6];
    const float* W1 = (const float*)d_in[7];
    const float* W2 = (const float*)d_in[8];
    const float* Ws = (const float*)d_in[9];
    float* out = (float*)d_out;

    const int E = in_sizes[0];
    const int D = 64;
    const int N = in_sizes[6] / D;
    const int ITERS = 10;

    char* ws = (char*)d_ws;
    size_t off = 0;
    auto carve = [&](size_t bytes) {
        void* p = ws + off;
        off += (bytes + 255) & ~(size_t)255;
        return p;
    };
    float* X0 = (float*)carve((size_t)N * D * sizeof(float));  // 25.6 MB
    float* X1 = (float*)carve((size_t)N * D * sizeof(float));  // 25.6 MB
    int* A_rp = (int*)carve((size_t)(N + 1) * sizeof(int));
    int* A_cs = (int*)carve((size_t)E * sizeof(int));
    float* A_vs = (float*)carve((size_t)E * sizeof(float));
    int* L_rp = (int*)carve((size_t)(N + 1) * sizeof(int));
    int* L_cs = (int*)carve((size_t)E * sizeof(int));
    float* L_vs = (float*)carve((size_t)E * sizeof(float));
    int* deg = (int*)carve((size_t)N * sizeof(int));
    int* nxt = (int*)carve((size_t)N * sizeof(int));
    float* v_cur = (float*)carve((size_t)N * sizeof(float));
    float* v_new = (float*)carve((size_t)N * sizeof(float));
    float* norms = (float*)carve(16 * sizeof(float));

    int e_blocks = (E + 255) / 256;
    int n_blocks = (N + 255) / 256;

    // ---- CSR build for A and L ----
    hipMemsetAsync(deg, 0, (size_t)N * sizeof(int), stream);
    hist_kernel<<<e_blocks, 256, 0, stream>>>(A_row, deg, E);
    scan_kernel<<<1, 1024, 0, stream>>>(deg, A_rp, nxt, N);
    scatter_kernel<<<e_blocks, 256, 0, stream>>>(A_row, A_col, A_val, nxt, A_cs, A_vs, E);

    hipMemsetAsync(deg, 0, (size_t)N * sizeof(int), stream);
    hist_kernel<<<e_blocks, 256, 0, stream>>>(L_row, deg, E);
    scan_kernel<<<1, 1024, 0, stream>>>(deg, L_rp, nxt, N);
    scatter_kernel<<<e_blocks, 256, 0, stream>>>(L_row, L_col, L_val, nxt, L_cs, L_vs, E);

    // ---- two fused residual GNN layers (layer 2 also emits scores) ----
    int fl_blocks = 2048;  // grid-stride; W staged once per block
    fused_layer_kernel<<<fl_blocks, 256, 0, stream>>>(
        A_rp, A_cs, A_vs, embed, W1, X0, nullptr, Ws, N);
    fused_layer_kernel<<<fl_blocks, 256, 0, stream>>>(
        A_rp, A_cs, A_vs, X0, W2, X1, v_cur, Ws, N);

    // ---- power iterations (normalize folded into scale) ----
    hipMemsetAsync(norms, 0, 16 * sizeof(float), stream);
    int p_blocks = (N * 16 + 255) / 256;
    float* cur = v_cur;
    float* nxt_v = v_new;
    for (int it = 0; it < ITERS; ++it) {
        power_iter_kernel<<<p_blocks, 256, 0, stream>>>(
            L_rp, L_cs, L_vs, cur, nxt_v,
            it ? (norms + it - 1) : nullptr, norms + it, N);
        float* t = cur; cur = nxt_v; nxt_v = t;
    }
    finalize_kernel<<<n_blocks, 256, 0, stream>>>(cur, norms + ITERS - 1, out, N);
}

// Round 4
// 1631.409 us; speedup vs baseline: 1.2539x; 1.2539x over previous
//
#include <hip/hip_runtime.h>
#include <hip/hip_bf16.h>
#include <math.h>

#define TAU 0.5f

// ---------------------------------------------------------------------------
// CSR build: histogram -> 3-phase parallel exclusive scan -> scatter.
// ---------------------------------------------------------------------------
__global__ void hist_kernel(const int* __restrict__ row, int* __restrict__ deg, int E) {
    int e = blockIdx.x * 256 + threadIdx.x;
    if (e < E) atomicAdd(&deg[row[e]], 1);
}

// Phase 1: per-block (1024-element tile) sums.
__global__ void scan_partial_kernel(const int* __restrict__ deg,
                                    int* __restrict__ blk_sum, int n) {
    int base = blockIdx.x * 1024;
    int t = threadIdx.x;  // 256
    int s = 0;
#pragma unroll
    for (int j = 0; j < 4; ++j) {
        int i = base + t * 4 + j;
        if (i < n) s += deg[i];
    }
    __shared__ int sh[256];
    sh[t] = s;
    __syncthreads();
    for (int off = 128; off; off >>= 1) {
        if (t < off) sh[t] += sh[t + off];
        __syncthreads();
    }
    if (t == 0) blk_sum[blockIdx.x] = sh[0];
}

// Phase 2: single small block scans the <=1024 block sums; writes row_ptr[n].
__global__ void scan_blk_kernel(const int* __restrict__ blk_sum,
                                int* __restrict__ blk_off,
                                int* __restrict__ row_ptr_n, int nb) {
    __shared__ int sh[1024];
    int t = threadIdx.x;  // 1024
    sh[t] = (t < nb) ? blk_sum[t] : 0;
    __syncthreads();
    for (int off = 1; off < 1024; off <<= 1) {
        int v = (t >= off) ? sh[t - off] : 0;
        __syncthreads();
        sh[t] += v;
        __syncthreads();
    }
    if (t < nb) blk_off[t] = (t == 0) ? 0 : sh[t - 1];
    if (t == 0) *row_ptr_n = sh[1023];
}

// Phase 3: per-tile exclusive scan + tile offset; writes row_ptr and next.
__global__ void scan_apply_kernel(const int* __restrict__ deg,
                                  const int* __restrict__ blk_off,
                                  int* __restrict__ row_ptr,
                                  int* __restrict__ next, int n) {
    int base = blockIdx.x * 1024;
    int t = threadIdx.x;  // 256
    int v[4];
    int s = 0;
#pragma unroll
    for (int j = 0; j < 4; ++j) {
        int i = base + t * 4 + j;
        v[j] = (i < n) ? deg[i] : 0;
        s += v[j];
    }
    __shared__ int sh[256];
    sh[t] = s;
    __syncthreads();
    for (int off = 1; off < 256; off <<= 1) {
        int x = (t >= off) ? sh[t - off] : 0;
        __syncthreads();
        sh[t] += x;
        __syncthreads();
    }
    int run = blk_off[blockIdx.x] + ((t == 0) ? 0 : sh[t - 1]);
#pragma unroll
    for (int j = 0; j < 4; ++j) {
        int i = base + t * 4 + j;
        if (i < n) { row_ptr[i] = run; next[i] = run; }
        run += v[j];
    }
}

__global__ void scatter_kernel(const int* __restrict__ row, const int* __restrict__ col,
                               const float* __restrict__ val, int* __restrict__ next,
                               int* __restrict__ col_s, float* __restrict__ val_s, int E) {
    int e = blockIdx.x * 256 + threadIdx.x;
    if (e >= E) return;
    int p = atomicAdd(&next[row[e]], 1);
    col_s[p] = col[e];
    val_s[p] = val[e];
}

// ---------------------------------------------------------------------------
// Fused GNN layer: one wave per row (grid-stride).
//   acc[lane] = sum_e val[e] * X[col[e], lane]        (CSR gather, unroll 4)
//   h[lane]   = sum_k acc[k] * W[lane, k]             (shfl matvec vs LDS W^T)
//   Xn[row]   = X[row] + relu(h)                      (residual, double-buffer)
//   if s: s[row] = dot(Xn[row], Ws)                   (folded score, layer 2)
// ---------------------------------------------------------------------------
__global__ void fused_layer_kernel(const int* __restrict__ row_ptr,
                                   const int* __restrict__ col_s,
                                   const float* __restrict__ val_s,
                                   const float* __restrict__ X,
                                   const float* __restrict__ W,
                                   float* __restrict__ Xn,
                                   float* __restrict__ s,
                                   const float* __restrict__ Wsv, int n) {
    __shared__ float Wt[64 * 65];
    int tid = threadIdx.x;
    for (int i = tid; i < 4096; i += 256) {
        int j = i >> 6, k = i & 63;     // W[j,k] row-major
        Wt[k * 65 + j] = W[i];          // transpose into LDS, stride 65
    }
    __syncthreads();
    int lane = tid & 63;
    int wv = tid >> 6;
    float wsl = (s != nullptr) ? Wsv[lane] : 0.f;
    int nwaves = gridDim.x * 4;
    for (int row = blockIdx.x * 4 + wv; row < n; row += nwaves) {
        int p = row_ptr[row];
        int end = row_ptr[row + 1];
        float a0 = 0.f, a1 = 0.f, a2 = 0.f, a3 = 0.f;
        for (; p + 4 <= end; p += 4) {
            int c0 = col_s[p], c1 = col_s[p + 1], c2 = col_s[p + 2], c3 = col_s[p + 3];
            float v0 = val_s[p], v1 = val_s[p + 1], v2 = val_s[p + 2], v3 = val_s[p + 3];
            a0 += v0 * X[(size_t)c0 * 64 + lane];
            a1 += v1 * X[(size_t)c1 * 64 + lane];
            a2 += v2 * X[(size_t)c2 * 64 + lane];
            a3 += v3 * X[(size_t)c3 * 64 + lane];
        }
        for (; p < end; ++p) a0 += val_s[p] * X[(size_t)col_s[p] * 64 + lane];
        float acc = (a0 + a1) + (a2 + a3);
        float h = 0.f;
#pragma unroll
        for (int k = 0; k < 64; ++k)
            h += __shfl(acc, k, 64) * Wt[k * 65 + lane];
        float xv = X[(size_t)row * 64 + lane] + fmaxf(h, 0.f);
        Xn[(size_t)row * 64 + lane] = xv;
        if (s != nullptr) {
            float d = xv * wsl;
            for (int off = 32; off; off >>= 1) d += __shfl_down(d, off, 64);
            if (lane == 0) s[row] = d;
        }
    }
}

// ---------------------------------------------------------------------------
// Fused power iteration: 16 lanes per row.
// ---------------------------------------------------------------------------
__global__ void power_iter_kernel(const int* __restrict__ row_ptr,
                                  const int* __restrict__ col_s,
                                  const float* __restrict__ val_s,
                                  const float* __restrict__ v_in,
                                  float* __restrict__ v_out,
                                  const float* __restrict__ norm_prev,
                                  float* __restrict__ norm_out, int n) {
    int g = blockIdx.x * 256 + threadIdx.x;
    int row = g >> 4;
    int t = g & 15;
    float sq = 0.f;
    if (row < n) {
        int p = row_ptr[row] + t;
        int end = row_ptr[row + 1];
        float s0 = 0.f;
        for (; p < end; p += 16) s0 += val_s[p] * v_in[col_s[p]];
        s0 += __shfl_xor(s0, 8, 16);
        s0 += __shfl_xor(s0, 4, 16);
        s0 += __shfl_xor(s0, 2, 16);
        s0 += __shfl_xor(s0, 1, 16);
        if (t == 0) {
            float scale = 1.f;
            if (norm_prev) scale = 1.f / fmaxf(sqrtf(*norm_prev), 1e-12f);
            float sg = (s0 > 0.f) ? 1.f : ((s0 < 0.f) ? -1.f : 0.f);
            float w = s0 * scale - TAU * sg;
            v_out[row] = w;
            sq = w * w;
        }
    }
    for (int off = 32; off; off >>= 1) sq += __shfl_down(sq, off, 64);
    __shared__ float sh[4];
    int lane = threadIdx.x & 63, wv = threadIdx.x >> 6;
    if (lane == 0) sh[wv] = sq;
    __syncthreads();
    if (threadIdx.x == 0) atomicAdd(norm_out, sh[0] + sh[1] + sh[2] + sh[3]);
}

// ---------------------------------------------------------------------------
// out[i] = v[i] / max(sqrt(ss), 1e-12)
// ---------------------------------------------------------------------------
__global__ void finalize_kernel(const float* __restrict__ v,
                                const float* __restrict__ norm_ptr,
                                float* __restrict__ out, int n) {
    int i = blockIdx.x * 256 + threadIdx.x;
    if (i >= n) return;
    float inv = 1.f / fmaxf(sqrtf(*norm_ptr), 1e-12f);
    out[i] = v[i] * inv;
}

extern "C" void kernel_launch(void* const* d_in, const int* in_sizes, int n_in,
                              void* d_out, int out_size, void* d_ws, size_t ws_size,
                              hipStream_t stream) {
    const int* A_row = (const int*)d_in[0];
    const int* A_col = (const int*)d_in[1];
    const float* A_val = (const float*)d_in[2];
    const int* L_row = (const int*)d_in[3];
    const int* L_col = (const int*)d_in[4];
    const float* L_val = (const float*)d_in[5];
    const float* embed = (const float*)d_in[6];
    const float* W1 = (const float*)d_in[7];
    const float* W2 = (const float*)d_in[8];
    const float* Ws = (const float*)d_in[9];
    float* out = (float*)d_out;

    const int E = in_sizes[0];
    const int D = 64;
    const int N = in_sizes[6] / D;
    const int ITERS = 10;

    char* ws = (char*)d_ws;
    size_t off = 0;
    auto carve = [&](size_t bytes) {
        void* p = ws + off;
        off += (bytes + 255) & ~(size_t)255;
        return p;
    };
    float* X0 = (float*)carve((size_t)N * D * sizeof(float));  // 25.6 MB
    float* X1 = (float*)carve((size_t)N * D * sizeof(float));  // 25.6 MB
    int* A_rp = (int*)carve((size_t)(N + 1) * sizeof(int));
    int* A_cs = (int*)carve((size_t)E * sizeof(int));
    float* A_vs = (float*)carve((size_t)E * sizeof(float));
    int* L_rp = (int*)carve((size_t)(N + 1) * sizeof(int));
    int* L_cs = (int*)carve((size_t)E * sizeof(int));
    float* L_vs = (float*)carve((size_t)E * sizeof(float));
    int* deg = (int*)carve((size_t)N * sizeof(int));
    int* nxt = (int*)carve((size_t)N * sizeof(int));
    int* blk_sum = (int*)carve(1024 * sizeof(int));
    int* blk_off = (int*)carve(1024 * sizeof(int));
    float* v_cur = (float*)carve((size_t)N * sizeof(float));
    float* v_new = (float*)carve((size_t)N * sizeof(float));
    float* norms = (float*)carve(16 * sizeof(float));

    int e_blocks = (E + 255) / 256;
    int n_blocks = (N + 255) / 256;
    int nb = (N + 1023) / 1024;  // scan tiles

    // ---- CSR build for A ----
    hipMemsetAsync(deg, 0, (size_t)N * sizeof(int), stream);
    hist_kernel<<<e_blocks, 256, 0, stream>>>(A_row, deg, E);
    scan_partial_kernel<<<nb, 256, 0, stream>>>(deg, blk_sum, N);
    scan_blk_kernel<<<1, 1024, 0, stream>>>(blk_sum, blk_off, A_rp + N, nb);
    scan_apply_kernel<<<nb, 256, 0, stream>>>(deg, blk_off, A_rp, nxt, N);
    scatter_kernel<<<e_blocks, 256, 0, stream>>>(A_row, A_col, A_val, nxt, A_cs, A_vs, E);

    // ---- CSR build for L ----
    hipMemsetAsync(deg, 0, (size_t)N * sizeof(int), stream);
    hist_kernel<<<e_blocks, 256, 0, stream>>>(L_row, deg, E);
    scan_partial_kernel<<<nb, 256, 0, stream>>>(deg, blk_sum, N);
    scan_blk_kernel<<<1, 1024, 0, stream>>>(blk_sum, blk_off, L_rp + N, nb);
    scan_apply_kernel<<<nb, 256, 0, stream>>>(deg, blk_off, L_rp, nxt, N);
    scatter_kernel<<<e_blocks, 256, 0, stream>>>(L_row, L_col, L_val, nxt, L_cs, L_vs, E);

    // ---- two fused residual GNN layers (layer 2 also emits scores) ----
    int fl_blocks = 2048;  // grid-stride; W staged once per block
    fused_layer_kernel<<<fl_blocks, 256, 0, stream>>>(
        A_rp, A_cs, A_vs, embed, W1, X0, nullptr, Ws, N);
    fused_layer_kernel<<<fl_blocks, 256, 0, stream>>>(
        A_rp, A_cs, A_vs, X0, W2, X1, v_cur, Ws, N);

    // ---- power iterations (normalize folded into scale) ----
    hipMemsetAsync(norms, 0, 16 * sizeof(float), stream);
    int p_blocks = (N * 16 + 255) / 256;
    float* cur = v_cur;
    float* nxt_v = v_new;
    for (int it = 0; it < ITERS; ++it) {
        power_iter_kernel<<<p_blocks, 256, 0, stream>>>(
            L_rp, L_cs, L_vs, cur, nxt_v,
            it ? (norms + it - 1) : nullptr, norms + it, N);
        float* t = cur; cur = nxt_v; nxt_v = t;
    }
    finalize_kernel<<<n_blocks, 256, 0, stream>>>(cur, norms + ITERS - 1, out, N);
}

// Round 5
// 1234.720 us; speedup vs baseline: 1.6568x; 1.3213x over previous
//
#include <hip/hip_runtime.h>
#include <hip/hip_bf16.h>
#include <math.h>

#define TAU 0.5f

// ---------------------------------------------------------------------------
// CSR build: histogram -> 3-phase parallel exclusive scan -> scatter.
// Edge payload packed as int2 {col, float_bits(val)}: one 8B store per edge.
// ---------------------------------------------------------------------------
__global__ void hist_kernel(const int* __restrict__ row, int* __restrict__ deg, int E) {
    int e = blockIdx.x * 256 + threadIdx.x;
    if (e < E) atomicAdd(&deg[row[e]], 1);
}

// Phase 1: per-block (1024-element tile) sums.
__global__ void scan_partial_kernel(const int* __restrict__ deg,
                                    int* __restrict__ blk_sum, int n) {
    int base = blockIdx.x * 1024;
    int t = threadIdx.x;  // 256
    int s = 0;
#pragma unroll
    for (int j = 0; j < 4; ++j) {
        int i = base + t * 4 + j;
        if (i < n) s += deg[i];
    }
    __shared__ int sh[256];
    sh[t] = s;
    __syncthreads();
    for (int off = 128; off; off >>= 1) {
        if (t < off) sh[t] += sh[t + off];
        __syncthreads();
    }
    if (t == 0) blk_sum[blockIdx.x] = sh[0];
}

// Phase 2: single small block scans the <=1024 block sums; writes row_ptr[n].
__global__ void scan_blk_kernel(const int* __restrict__ blk_sum,
                                int* __restrict__ blk_off,
                                int* __restrict__ row_ptr_n, int nb) {
    __shared__ int sh[1024];
    int t = threadIdx.x;  // 1024
    sh[t] = (t < nb) ? blk_sum[t] : 0;
    __syncthreads();
    for (int off = 1; off < 1024; off <<= 1) {
        int v = (t >= off) ? sh[t - off] : 0;
        __syncthreads();
        sh[t] += v;
        __syncthreads();
    }
    if (t < nb) blk_off[t] = (t == 0) ? 0 : sh[t - 1];
    if (t == 0) *row_ptr_n = sh[1023];
}

// Phase 3: per-tile exclusive scan + tile offset; writes row_ptr and next.
__global__ void scan_apply_kernel(const int* __restrict__ deg,
                                  const int* __restrict__ blk_off,
                                  int* __restrict__ row_ptr,
                                  int* __restrict__ next, int n) {
    int base = blockIdx.x * 1024;
    int t = threadIdx.x;  // 256
    int v[4];
    int s = 0;
#pragma unroll
    for (int j = 0; j < 4; ++j) {
        int i = base + t * 4 + j;
        v[j] = (i < n) ? deg[i] : 0;
        s += v[j];
    }
    __shared__ int sh[256];
    sh[t] = s;
    __syncthreads();
    for (int off = 1; off < 256; off <<= 1) {
        int x = (t >= off) ? sh[t - off] : 0;
        __syncthreads();
        sh[t] += x;
        __syncthreads();
    }
    int run = blk_off[blockIdx.x] + ((t == 0) ? 0 : sh[t - 1]);
#pragma unroll
    for (int j = 0; j < 4; ++j) {
        int i = base + t * 4 + j;
        if (i < n) { row_ptr[i] = run; next[i] = run; }
        run += v[j];
    }
}

__global__ void scatter_kernel(const int* __restrict__ row, const int* __restrict__ col,
                               const float* __restrict__ val, int* __restrict__ next,
                               int2* __restrict__ cv, int E) {
    int e = blockIdx.x * 256 + threadIdx.x;
    if (e >= E) return;
    int p = atomicAdd(&next[row[e]], 1);
    cv[p] = make_int2(col[e], __float_as_int(val[e]));
}

// ---------------------------------------------------------------------------
// Fused GNN layer: one wave per row (grid-stride).
//   acc[lane] = sum_e val[e] * X[col[e], lane]        (CSR gather, unroll 4)
//   h[lane]   = sum_k acc[k] * W[lane, k]             (shfl matvec vs LDS W^T)
//   Xn[row]   = X[row] + relu(h)                      (residual, double-buffer)
//   if s: s[row] = dot(Xn[row], Ws)                   (folded score, layer 2)
// ---------------------------------------------------------------------------
__global__ void fused_layer_kernel(const int* __restrict__ row_ptr,
                                   const int2* __restrict__ cv,
                                   const float* __restrict__ X,
                                   const float* __restrict__ W,
                                   float* __restrict__ Xn,
                                   float* __restrict__ s,
                                   const float* __restrict__ Wsv, int n) {
    __shared__ float Wt[64 * 65];
    int tid = threadIdx.x;
    for (int i = tid; i < 4096; i += 256) {
        int j = i >> 6, k = i & 63;     // W[j,k] row-major
        Wt[k * 65 + j] = W[i];          // transpose into LDS, stride 65
    }
    __syncthreads();
    int lane = tid & 63;
    int wv = tid >> 6;
    float wsl = (s != nullptr) ? Wsv[lane] : 0.f;
    int nwaves = gridDim.x * 4;
    for (int row = blockIdx.x * 4 + wv; row < n; row += nwaves) {
        int p = row_ptr[row];
        int end = row_ptr[row + 1];
        float a0 = 0.f, a1 = 0.f, a2 = 0.f, a3 = 0.f;
        for (; p + 4 <= end; p += 4) {
            int2 e0 = cv[p], e1 = cv[p + 1], e2 = cv[p + 2], e3 = cv[p + 3];
            a0 += __int_as_float(e0.y) * X[(size_t)e0.x * 64 + lane];
            a1 += __int_as_float(e1.y) * X[(size_t)e1.x * 64 + lane];
            a2 += __int_as_float(e2.y) * X[(size_t)e2.x * 64 + lane];
            a3 += __int_as_float(e3.y) * X[(size_t)e3.x * 64 + lane];
        }
        for (; p < end; ++p) {
            int2 e0 = cv[p];
            a0 += __int_as_float(e0.y) * X[(size_t)e0.x * 64 + lane];
        }
        float acc = (a0 + a1) + (a2 + a3);
        float h = 0.f;
#pragma unroll
        for (int k = 0; k < 64; ++k)
            h += __shfl(acc, k, 64) * Wt[k * 65 + lane];
        float xv = X[(size_t)row * 64 + lane] + fmaxf(h, 0.f);
        Xn[(size_t)row * 64 + lane] = xv;
        if (s != nullptr) {
            float d = xv * wsl;
            for (int off = 32; off; off >>= 1) d += __shfl_down(d, off, 64);
            if (lane == 0) s[row] = d;
        }
    }
}

// ---------------------------------------------------------------------------
// Fused power iteration: 16 lanes per row.
//   scale = prev inv-norm, summed from 64 partial slots (wave shuffle).
//   norm written to 64 slots (atomicAdd contention ~98 blocks/slot).
// ---------------------------------------------------------------------------
__global__ void power_iter_kernel(const int* __restrict__ row_ptr,
                                  const int2* __restrict__ cv,
                                  const float* __restrict__ v_in,
                                  float* __restrict__ v_out,
                                  const float* __restrict__ norm_prev,  // 64 slots or null
                                  float* __restrict__ norm_out,         // 64 slots
                                  int n) {
    int lane = threadIdx.x & 63;
    float scale = 1.f;
    if (norm_prev) {
        float x = norm_prev[lane];
#pragma unroll
        for (int off = 32; off; off >>= 1) x += __shfl_xor(x, off, 64);
        scale = 1.f / fmaxf(sqrtf(x), 1e-12f);
    }
    int g = blockIdx.x * 256 + threadIdx.x;
    int row = g >> 4;
    int t = g & 15;
    float sq = 0.f;
    if (row < n) {
        int p = row_ptr[row] + t;
        int end = row_ptr[row + 1];
        float s0 = 0.f;
        for (; p < end; p += 16) {
            int2 e = cv[p];
            s0 += __int_as_float(e.y) * v_in[e.x];
        }
        s0 += __shfl_xor(s0, 8, 16);
        s0 += __shfl_xor(s0, 4, 16);
        s0 += __shfl_xor(s0, 2, 16);
        s0 += __shfl_xor(s0, 1, 16);
        if (t == 0) {
            float sg = (s0 > 0.f) ? 1.f : ((s0 < 0.f) ? -1.f : 0.f);
            float w = s0 * scale - TAU * sg;
            v_out[row] = w;
            sq = w * w;
        }
    }
    for (int off = 32; off; off >>= 1) sq += __shfl_down(sq, off, 64);
    __shared__ float sh[4];
    int wv = threadIdx.x >> 6;
    if (lane == 0) sh[wv] = sq;
    __syncthreads();
    if (threadIdx.x == 0)
        atomicAdd(&norm_out[blockIdx.x & 63], sh[0] + sh[1] + sh[2] + sh[3]);
}

// ---------------------------------------------------------------------------
// out[i] = v[i] * inv_norm (norm from 64 partial slots).
// ---------------------------------------------------------------------------
__global__ void finalize_kernel(const float* __restrict__ v,
                                const float* __restrict__ slots,
                                float* __restrict__ out, int n) {
    int lane = threadIdx.x & 63;
    float x = slots[lane];
#pragma unroll
    for (int off = 32; off; off >>= 1) x += __shfl_xor(x, off, 64);
    float inv = 1.f / fmaxf(sqrtf(x), 1e-12f);
    int i = blockIdx.x * 256 + threadIdx.x;
    if (i < n) out[i] = v[i] * inv;
}

extern "C" void kernel_launch(void* const* d_in, const int* in_sizes, int n_in,
                              void* d_out, int out_size, void* d_ws, size_t ws_size,
                              hipStream_t stream) {
    const int* A_row = (const int*)d_in[0];
    const int* A_col = (const int*)d_in[1];
    const float* A_val = (const float*)d_in[2];
    const int* L_row = (const int*)d_in[3];
    const int* L_col = (const int*)d_in[4];
    const float* L_val = (const float*)d_in[5];
    const float* embed = (const float*)d_in[6];
    const float* W1 = (const float*)d_in[7];
    const float* W2 = (const float*)d_in[8];
    const float* Ws = (const float*)d_in[9];
    float* out = (float*)d_out;

    const int E = in_sizes[0];
    const int D = 64;
    const int N = in_sizes[6] / D;
    const int ITERS = 10;

    char* ws = (char*)d_ws;
    size_t off = 0;
    auto carve = [&](size_t bytes) {
        void* p = ws + off;
        off += (bytes + 255) & ~(size_t)255;
        return p;
    };
    float* X0 = (float*)carve((size_t)N * D * sizeof(float));  // 25.6 MB
    float* X1 = (float*)carve((size_t)N * D * sizeof(float));  // 25.6 MB
    int* A_rp = (int*)carve((size_t)(N + 1) * sizeof(int));
    int2* A_cv = (int2*)carve((size_t)E * sizeof(int2));
    int* L_rp = (int*)carve((size_t)(N + 1) * sizeof(int));
    int2* L_cv = (int2*)carve((size_t)E * sizeof(int2));
    int* deg = (int*)carve((size_t)N * sizeof(int));
    int* nxt = (int*)carve((size_t)N * sizeof(int));
    int* blk_sum = (int*)carve(1024 * sizeof(int));
    int* blk_off = (int*)carve(1024 * sizeof(int));
    float* v_cur = (float*)carve((size_t)N * sizeof(float));
    float* v_new = (float*)carve((size_t)N * sizeof(float));
    float* norms = (float*)carve((size_t)ITERS * 64 * sizeof(float));

    int e_blocks = (E + 255) / 256;
    int n_blocks = (N + 255) / 256;
    int nb = (N + 1023) / 1024;  // scan tiles

    // ---- CSR build for A ----
    hipMemsetAsync(deg, 0, (size_t)N * sizeof(int), stream);
    hist_kernel<<<e_blocks, 256, 0, stream>>>(A_row, deg, E);
    scan_partial_kernel<<<nb, 256, 0, stream>>>(deg, blk_sum, N);
    scan_blk_kernel<<<1, 1024, 0, stream>>>(blk_sum, blk_off, A_rp + N, nb);
    scan_apply_kernel<<<nb, 256, 0, stream>>>(deg, blk_off, A_rp, nxt, N);
    scatter_kernel<<<e_blocks, 256, 0, stream>>>(A_row, A_col, A_val, nxt, A_cv, E);

    // ---- CSR build for L ----
    hipMemsetAsync(deg, 0, (size_t)N * sizeof(int), stream);
    hist_kernel<<<e_blocks, 256, 0, stream>>>(L_row, deg, E);
    scan_partial_kernel<<<nb, 256, 0, stream>>>(deg, blk_sum, N);
    scan_blk_kernel<<<1, 1024, 0, stream>>>(blk_sum, blk_off, L_rp + N, nb);
    scan_apply_kernel<<<nb, 256, 0, stream>>>(deg, blk_off, L_rp, nxt, N);
    scatter_kernel<<<e_blocks, 256, 0, stream>>>(L_row, L_col, L_val, nxt, L_cv, E);

    // ---- two fused residual GNN layers (layer 2 also emits scores) ----
    int fl_blocks = 2048;  // grid-stride; W staged once per block
    fused_layer_kernel<<<fl_blocks, 256, 0, stream>>>(
        A_rp, A_cv, embed, W1, X0, nullptr, Ws, N);
    fused_layer_kernel<<<fl_blocks, 256, 0, stream>>>(
        A_rp, A_cv, X0, W2, X1, v_cur, Ws, N);

    // ---- power iterations (normalize folded; 64-slot norm partials) ----
    hipMemsetAsync(norms, 0, (size_t)ITERS * 64 * sizeof(float), stream);
    int p_blocks = (N * 16 + 255) / 256;
    float* cur = v_cur;
    float* nxt_v = v_new;
    for (int it = 0; it < ITERS; ++it) {
        power_iter_kernel<<<p_blocks, 256, 0, stream>>>(
            L_rp, L_cv, cur, nxt_v,
            it ? (norms + (it - 1) * 64) : nullptr, norms + it * 64, N);
        float* t = cur; cur = nxt_v; nxt_v = t;
    }
    finalize_kernel<<<n_blocks, 256, 0, stream>>>(cur, norms + (ITERS - 1) * 64, out, N);
}